// Round 14
// baseline (551.172 us; speedup 1.0000x reference)
//
#include <hip/hip_runtime.h>

typedef _Float16 f16;
typedef f16 f16x8 __attribute__((ext_vector_type(8)));
typedef f16 f16x4 __attribute__((ext_vector_type(4)));
typedef float f32x4 __attribute__((ext_vector_type(4)));

#define B_ 4
#define T_ 512
#define DM_ 768
#define H_ 8
#define DQ_ 32
#define FF_ 3072
#define L_ 6
#define OUT_ 80
#define M_ (B_*T_)   // 2048 tokens

// async global->LDS, 16B per lane; LDS dest is wave-uniform base + lane*16 (linear)
__device__ __forceinline__ void gload16(const f16* g, f16* l) {
    __builtin_amdgcn_global_load_lds(
        (const __attribute__((address_space(1))) unsigned int*)g,
        (__attribute__((address_space(3))) unsigned int*)l, 16, 0, 0);
}

template<int N> __device__ __forceinline__ void wait_vm() {
    if constexpr (N == 0)      asm volatile("s_waitcnt vmcnt(0)" ::: "memory");
    else if constexpr (N == 3) asm volatile("s_waitcnt vmcnt(3)" ::: "memory");
    else if constexpr (N == 4) asm volatile("s_waitcnt vmcnt(4)" ::: "memory");
    else if constexpr (N == 6) asm volatile("s_waitcnt vmcnt(6)" ::: "memory");
    else                       asm volatile("s_waitcnt vmcnt(0)" ::: "memory");
}

// ---------------- single fused pack kernel (R13 structure + nontemporal stores) ----------------

#define PKU_X  98304L                      // x: units of 16 floats
#define PKU_L1 (PKU_X + 884736L)           // + lin1w
#define PKU_L2 (PKU_L1 + 884736L)          // + lin2w = 1867776
#define PKB_VEC 7296                       // PKU_L2 / 256
#define PKB_LIN 1632                       // (98304 woutH + 319488 relH) / 256
#define PKB_QKV 864                        // 72 (l,sec,hpair) groups * 12 k-tiles of 64
#define PKB_WO  1152                       // 6l * 8 k'-tiles * 24 n-tiles (32x32)
#define PKB_TOTAL (PKB_VEC + PKB_LIN + PKB_QKV + PKB_WO)

__global__ void pack_all_kernel(
    const float* __restrict__ x, const float* __restrict__ wq, const float* __restrict__ wk,
    const float* __restrict__ wv, const float* __restrict__ wo, const float* __restrict__ rel,
    const float* __restrict__ lin1w, const float* __restrict__ lin2w, const float* __restrict__ wout,
    f16* __restrict__ xH, f16* __restrict__ BTqkv, f16* __restrict__ BTwo,
    f16* __restrict__ lin1H, f16* __restrict__ lin2H, f16* __restrict__ woutH, f16* __restrict__ relH)
{
    __shared__ float tile[64 * 65];
    const int bid = blockIdx.x, tid = threadIdx.x;
    if (bid < PKB_VEC) {
        const long u = (long)bid * 256 + tid;   // unit of 16 floats
        const float* src; f16* dst; long off;
        if (u < PKU_X)       { src = x;     dst = xH;    off = u; }
        else if (u < PKU_L1) { src = lin1w; dst = lin1H; off = u - PKU_X; }
        else                 { src = lin2w; dst = lin2H; off = u - PKU_L1; }
        const float4 v0 = ((const float4*)src)[off * 4];
        const float4 v1 = ((const float4*)src)[off * 4 + 1];
        const float4 v2 = ((const float4*)src)[off * 4 + 2];
        const float4 v3 = ((const float4*)src)[off * 4 + 3];
        f16x8 o0, o1;
        o0[0] = (f16)v0.x; o0[1] = (f16)v0.y; o0[2] = (f16)v0.z; o0[3] = (f16)v0.w;
        o0[4] = (f16)v1.x; o0[5] = (f16)v1.y; o0[6] = (f16)v1.z; o0[7] = (f16)v1.w;
        o1[0] = (f16)v2.x; o1[1] = (f16)v2.y; o1[2] = (f16)v2.z; o1[3] = (f16)v2.w;
        o1[4] = (f16)v3.x; o1[5] = (f16)v3.y; o1[6] = (f16)v3.z; o1[7] = (f16)v3.w;
        __builtin_nontemporal_store(o0, (f16x8*)dst + off * 2);
        __builtin_nontemporal_store(o1, (f16x8*)dst + off * 2 + 1);
    } else if (bid < PKB_VEC + PKB_LIN) {
        const long u = (long)(bid - PKB_VEC) * 256 + tid;
        if (u < 98304) {            // woutH zero-padded (128,768)
            const int k = (int)(u % 768), n = (int)(u / 768);
            woutH[u] = (n < OUT_) ? (f16)wout[n * 768 + k] : (f16)0;
        } else {                    // relH[l][h][208][32], rows d>=199 zero
            const long v2 = u - 98304;
            const int a = (int)(v2 & 31);
            const long t = v2 >> 5;
            const int d = (int)(t % 208);
            const int lh = (int)(t / 208);
            relH[v2] = (d < 199) ? (f16)rel[((long)lh * 199 + d) * 32 + a] : (f16)0;
        }
    } else if (bid < PKB_VEC + PKB_LIN + PKB_QKV) {
        // BTqkv: per (l,sec,h-pair), transpose a 64k x 64n fp32 region (two 64x32 head panels)
        const int g = bid - (PKB_VEC + PKB_LIN);
        const int kb = g % 12;
        const int grp = g / 12;
        const int hp = grp & 3, sec = (grp >> 2) % 3, l = grp / 12;
        const float* w = (sec == 0) ? wq : (sec == 1 ? wk : wv);
        const float scale = (sec == 0) ? 0.17677669529663687f : 1.f;
#pragma unroll
        for (int hh = 0; hh < 2; ++hh) {
            const float* src = w + (((long)l * 8 + hp * 2 + hh) * 768 + kb * 64) * 32;
#pragma unroll
            for (int p = 0; p < 2; ++p) {
                const int kk = p * 32 + (tid >> 3), a = (tid & 7) * 4;
                const float4 v = *(const float4*)(src + (long)kk * 32 + a);
                float* t = &tile[kk * 65 + hh * 32 + a];
                t[0] = v.x * scale; t[1] = v.y * scale; t[2] = v.z * scale; t[3] = v.w * scale;
            }
        }
        __syncthreads();
        f16* dst = BTqkv + ((long)l * 768 + sec * 256 + hp * 64) * 768 + kb * 64;
#pragma unroll
        for (int p = 0; p < 2; ++p) {
            const int nn = p * 32 + (tid >> 3), k8 = (tid & 7) * 8;
            f16x8 o;
#pragma unroll
            for (int e = 0; e < 8; ++e) o[e] = (f16)tile[(k8 + e) * 65 + nn];
            __builtin_nontemporal_store(o, (f16x8*)(dst + (long)nn * 768 + k8));
        }
    } else {
        // BTwo: transpose wo[l][k'][n] 32x32 fp32 tiles -> BTwo[l][n][k']
        const int g = bid - (PKB_VEC + PKB_LIN + PKB_QKV);
        const int nb = g % 24;
        const int tmp = g / 24;
        const int kb2 = tmp % 8, l = tmp / 8;
        const float* src = wo + ((long)l * 256 + kb2 * 32) * 768 + nb * 32;
        {
            const int r = tid >> 3, c = (tid & 7) * 4;
            const float4 v = *(const float4*)(src + (long)r * 768 + c);
            float* t = &tile[r * 65 + c];
            t[0] = v.x; t[1] = v.y; t[2] = v.z; t[3] = v.w;
        }
        __syncthreads();
        if (tid < 128) {
            const int n = tid >> 2, k8 = (tid & 3) * 8;
            f16x8 o;
#pragma unroll
            for (int e = 0; e < 8; ++e) o[e] = (f16)tile[(k8 + e) * 65 + n];
            f16* dst = BTwo + ((long)l * 768 + nb * 32 + n) * 256 + kb2 * 32 + k8;
            __builtin_nontemporal_store(o, (f16x8*)dst);
        }
    }
}

// ---------------- bijective XCD chunk swizzle (nwg %8==0 for all our grids) ----------------
__device__ __forceinline__ void xcd_tile(int BM, int BN, int& m0, int& n0) {
    const int gx = gridDim.x;
    const int id = blockIdx.y * gx + blockIdx.x;
    const int cpx = (gx * gridDim.y) >> 3;
    const int t = (id & 7) * cpx + (id >> 3);
    m0 = (t / gx) * BM;
    n0 = (t % gx) * BN;
}

// ---------------- gemm7: 2-buffer, 2-barrier, counted vmcnt, XOR-swizzled LDS ----------------
// mode: 1=+bias, 2=+res, 4=ReLU, 8=outF, 16=outH, 32=qkv epilogue, 64=split-K f16 partial (outH)

template<int BM, int BN>
__global__ __launch_bounds__(256) void gemm7_kernel(
    const f16* __restrict__ A, const f16* __restrict__ Bt,
    const float* __restrict__ bias, const float* __restrict__ res,
    float* __restrict__ outF, f16* __restrict__ outH, f16* __restrict__ vTout,
    int M, int N, int K, int mode, int ldOut, int nMax)
{
    constexpr int IA = BM / 32;
    constexpr int JF = BN / 32;
    constexpr int LA = BM / 32;
    constexpr int LB = BN / 32;
    constexpr int L  = LA + LB;
    __shared__ __align__(16) f16 As[2][BM * 64];
    __shared__ __align__(16) f16 Bs[2][BN * 64];
    const int tid = threadIdx.x;
    const int wave = tid >> 6, lane = tid & 63;
    int m0, n0; xcd_tile(BM, BN, m0, n0);
    const int z = blockIdx.z;
    const int Kl = K / (int)gridDim.z;
    const int kb = z * Kl;
    const int nt = Kl / 64;
    const int wr = wave >> 1, wc = wave & 1;
    const int l15 = lane & 15, l4 = lane >> 4;
    const int lrow = lane >> 3;
    const int lcol = ((lane & 7) ^ (lane >> 3)) * 8;   // pre-swizzled source granule

    const f16* Abase = A  + (long)(m0 + lrow) * K + kb + lcol;
    const f16* Bbase = Bt + (long)(n0 + lrow) * K + kb + lcol;

    f32x4 acc[IA][JF];
#pragma unroll
    for (int i = 0; i < IA; ++i)
#pragma unroll
        for (int j = 0; j < JF; ++j) acc[i][j] = (f32x4){0.f, 0.f, 0.f, 0.f};

    auto stage = [&](int buf, int k0) {
#pragma unroll
        for (int i = 0; i < LA; ++i) {
            const int c = wave + 4 * i;
            gload16(Abase + (long)c * 8 * K + k0, &As[buf][c * 512]);
        }
#pragma unroll
        for (int i = 0; i < LB; ++i) {
            const int c = wave + 4 * i;
            gload16(Bbase + (long)c * 8 * K + k0, &Bs[buf][c * 512]);
        }
    };

    stage(0, 0);
    int cur = 0;
    for (int t = 0; t < nt; ++t) {
        if (t + 1 < nt) { stage(cur ^ 1, (t + 1) * 64); wait_vm<L>(); }
        else            { wait_vm<0>(); }
        __builtin_amdgcn_s_barrier();
#pragma unroll
        for (int s = 0; s < 2; ++s) {
            f16x8 af[IA], bf[JF];
#pragma unroll
            for (int i = 0; i < IA; ++i) {
                const int row = wr * (BM / 2) + i * 16 + l15;
                af[i] = *(const f16x8*)&As[cur][row * 64 + (((s * 4 + l4) ^ (l15 & 7)) * 8)];
            }
#pragma unroll
            for (int j = 0; j < JF; ++j) {
                const int row = wc * (BN / 2) + j * 16 + l15;
                bf[j] = *(const f16x8*)&Bs[cur][row * 64 + (((s * 4 + l4) ^ (l15 & 7)) * 8)];
            }
#pragma unroll
            for (int i = 0; i < IA; ++i)
#pragma unroll
                for (int j = 0; j < JF; ++j)
                    acc[i][j] = __builtin_amdgcn_mfma_f32_16x16x32_f16(af[i], bf[j], acc[i][j], 0, 0, 0);
        }
        __builtin_amdgcn_s_barrier();
        cur ^= 1;
    }

#pragma unroll
    for (int i = 0; i < IA; ++i) {
#pragma unroll
        for (int j = 0; j < JF; ++j) {
            const int col = n0 + wc * (BN / 2) + j * 16 + l15;
            if (mode & 64) {
                f16* po = outH + (long)z * M * ldOut;   // f16 split-K partial
#pragma unroll
                for (int r = 0; r < 4; ++r) {
                    const int row = m0 + wr * (BM / 2) + i * 16 + l4 * 4 + r;
                    po[(long)row * ldOut + col] = (f16)acc[i][j][r];
                }
            } else if (col < nMax) {
                const float bvv = (mode & 1) ? bias[col] : 0.f;
#pragma unroll
                for (int r = 0; r < 4; ++r) {
                    const int row = m0 + wr * (BM / 2) + i * 16 + l4 * 4 + r;
                    float v = acc[i][j][r] + bvv;
                    if (mode & 2) v += res[(long)row * N + col];
                    if (mode & 4) v = fmaxf(v, 0.f);
                    if (mode & 8)  outF[(long)row * ldOut + col] = v;
                    if (mode & 16) outH[(long)row * ldOut + col] = (f16)v;
                }
            }
        }
    }
}

// ---------------- gemm8: BM=32,BN=64,BK=128 wave-split-K (kw halves K, wc halves N) ----------------
// Doubles MFMA per barrier-pair (8 vs 4) at the same 768-block grid. LDS 48 KB -> 3 blocks/CU.
// LDS layout: row*128 + (granule ^ (row&7))*8, staged via pre-swizzled global source (rule #21).
// Epilogue: kw=1 waves dump acc to LDS (stride-17), kw=0 waves reduce + write.
// mode: 1=+bias, 2=+res, 8=outF, 32=qkv epilogue.

__global__ __launch_bounds__(256) void gemm8_kernel(
    const f16* __restrict__ A, const f16* __restrict__ Bt,
    const float* __restrict__ bias, const float* __restrict__ res,
    float* __restrict__ outF, f16* __restrict__ outH, f16* __restrict__ vTout,
    int M, int N, int K, int mode, int ldOut, int nMax)
{
    __shared__ __align__(16) f16 As[2][32 * 128];   // 16 KB
    __shared__ __align__(16) f16 Bs[2][64 * 128];   // 32 KB
    const int tid = threadIdx.x;
    const int wave = tid >> 6, lane = tid & 63;
    int m0, n0; xcd_tile(32, 64, m0, n0);
    const int nt = K / 128;
    const int kw = wave >> 1, wc = wave & 1;
    const int l15 = lane & 15, l4 = lane >> 4;
    const int srow = lane >> 4;          // row within 4-row staging chunk

    f32x4 acc[2][2];
#pragma unroll
    for (int i = 0; i < 2; ++i)
#pragma unroll
        for (int j = 0; j < 2; ++j) acc[i][j] = (f32x4){0.f, 0.f, 0.f, 0.f};

    auto stage = [&](int buf, int k0) {
#pragma unroll
        for (int i = 0; i < 2; ++i) {    // A: 8 chunks / 4 waves
            const int c = wave + 4 * i;
            const int gsw = (lane & 15) ^ ((c * 4 + srow) & 7);
            gload16(A + (long)(m0 + c * 4 + srow) * K + k0 + gsw * 8, &As[buf][c * 512]);
        }
#pragma unroll
        for (int i = 0; i < 4; ++i) {    // B: 16 chunks / 4 waves
            const int c = wave + 4 * i;
            const int gsw = (lane & 15) ^ ((c * 4 + srow) & 7);
            gload16(Bt + (long)(n0 + c * 4 + srow) * K + k0 + gsw * 8, &Bs[buf][c * 512]);
        }
    };

    stage(0, 0);
    int cur = 0;
    for (int t = 0; t < nt; ++t) {
        if (t + 1 < nt) { stage(cur ^ 1, (t + 1) * 128); wait_vm<6>(); }
        else            { wait_vm<0>(); }
        __builtin_amdgcn_s_barrier();
#pragma unroll
        for (int s = 0; s < 2; ++s) {
            f16x8 af[2], bf[2];
#pragma unroll
            for (int i = 0; i < 2; ++i) {
                const int row = i * 16 + l15;
                af[i] = *(const f16x8*)&As[cur][row * 128 + (((kw * 8 + s * 4 + l4) ^ (row & 7)) * 8)];
            }
#pragma unroll
            for (int j = 0; j < 2; ++j) {
                const int row = wc * 32 + j * 16 + l15;
                bf[j] = *(const f16x8*)&Bs[cur][row * 128 + (((kw * 8 + s * 4 + l4) ^ (row & 7)) * 8)];
            }
#pragma unroll
            for (int i = 0; i < 2; ++i)
#pragma unroll
                for (int j = 0; j < 2; ++j)
                    acc[i][j] = __builtin_amdgcn_mfma_f32_16x16x32_f16(af[i], bf[j], acc[i][j], 0, 0, 0);
        }
        __builtin_amdgcn_s_barrier();
        cur ^= 1;
    }

    // cross-kw reduction through LDS (stride 17 floats to spread banks)
    float* red = (float*)&As[0][0];      // 4096 floats available, need <= 127*17+16
    if (kw == 1) {
        const int base = (wc * 64 + lane) * 17;
#pragma unroll
        for (int i = 0; i < 2; ++i)
#pragma unroll
            for (int j = 0; j < 2; ++j)
#pragma unroll
                for (int r = 0; r < 4; ++r)
                    red[base + i * 8 + j * 4 + r] = acc[i][j][r];
    }
    __syncthreads();
    if (kw != 0) return;
    const int base = (wc * 64 + lane) * 17;
#pragma unroll
    for (int i = 0; i < 2; ++i)
#pragma unroll
        for (int j = 0; j < 2; ++j)
#pragma unroll
            for (int r = 0; r < 4; ++r)
                acc[i][j][r] += red[base + i * 8 + j * 4 + r];

#pragma unroll
    for (int i = 0; i < 2; ++i) {
#pragma unroll
        for (int j = 0; j < 2; ++j) {
            const int col = n0 + wc * 32 + j * 16 + l15;
            if (mode & 32) {
#pragma unroll
                for (int r = 0; r < 4; ++r) {
                    const int row = m0 + i * 16 + l4 * 4 + r;
                    float v = acc[i][j][r];
                    if (col < 512) {
                        outH[(long)row * 512 + col] = (f16)v;
                    } else {
                        const int bb = row >> 9, t = row & 511;
                        vTout[((long)(bb * 256 + (col - 512))) * 512 + t] = (f16)v;
                    }
                }
            } else if (col < nMax) {
                const float bvv = (mode & 1) ? bias[col] : 0.f;
#pragma unroll
                for (int r = 0; r < 4; ++r) {
                    const int row = m0 + i * 16 + l4 * 4 + r;
                    float v = acc[i][j][r] + bvv;
                    if (mode & 2) v += res[(long)row * N + col];
                    if (mode & 8) outF[(long)row * ldOut + col] = v;
                }
            }
        }
    }
}

// ---------------- banded attention via MFMA (unchanged from R13) ----------------

__global__ __launch_bounds__(256) void attn_kernel(
    const f16* __restrict__ qkvH, const f16* __restrict__ vT,
    const f16* __restrict__ relH, int l, f16* __restrict__ o)
{
    __shared__ __align__(16) f16 Ks[272 * 40];
    __shared__ __align__(16) f16 Vt[32 * 296];
    __shared__ __align__(16) f16 Scr[64 * 296];
    const int tid = threadIdx.x;
    const int qb = blockIdx.x, h = blockIdx.y, b = blockIdx.z;
    const int q0 = qb * 64;
    int lo = q0 - 99; lo = (lo > 0) ? (lo & ~7) : 0;
    const int hi = min(512, q0 + 163);
    const int nk = hi - lo;                             // <= 269

    for (int idx = tid; idx < 272 * 4; idx += 256) {
        const int r = idx >> 2, c = idx & 3;
        f16x8 v = {};
        if (r < nk)
            v = *(const f16x8*)(qkvH + ((long)(b * 512 + lo + r)) * 512 + 256 + h * 32 + c * 8);
        *(f16x8*)&Ks[r * 40 + c * 8] = v;
    }
    for (int idx = tid; idx < 32 * 36; idx += 256) {
        const int a = idx / 36, k8 = idx % 36;
        f16x8 v = {};
        const int kbase = k8 * 8;
        if (kbase < nk) {
            const f16* src = vT + ((long)(b * 256 + h * 32 + a)) * 512 + lo + kbase;
            if (kbase + 8 <= nk) {
                v = *(const f16x8*)src;
            } else {
#pragma unroll
                for (int e = 0; e < 8; ++e) if (kbase + e < nk) v[e] = src[e];
            }
        }
        *(f16x8*)&Vt[a * 296 + kbase] = v;
    }

    const int wave = tid >> 6, lane = tid & 63;
    const int l15 = lane & 15, l4 = lane >> 4;
    const int qloc = wave * 16;

    const f16x8 qf = *(const f16x8*)(qkvH + ((long)(b * 512 + q0 + qloc + l15)) * 512 + h * 32 + l4 * 8);

    const f16* relh = relH + ((long)(l * 8 + h)) * 208 * 32;
    {
        f32x4 racc[13];
#pragma unroll
        for (int fd = 0; fd < 13; ++fd) {
            const f16x8 bf = *(const f16x8*)(relh + (fd * 16 + l15) * 32 + l4 * 8);
            racc[fd] = __builtin_amdgcn_mfma_f32_16x16x32_f16(qf, bf, (f32x4){0.f,0.f,0.f,0.f}, 0, 0, 0);
        }
#pragma unroll
        for (int fd = 0; fd < 13; ++fd)
#pragma unroll
            for (int r = 0; r < 4; ++r)
                Scr[(qloc + l4 * 4 + r) * 296 + fd * 16 + l15] = (f16)racc[fd][r];
    }
    __syncthreads();

    f32x4 sacc[17];
#pragma unroll
    for (int fk = 0; fk < 17; ++fk) {
        const f16x8 bf = *(const f16x8*)&Ks[(fk * 16 + l15) * 40 + l4 * 8];
        sacc[fk] = __builtin_amdgcn_mfma_f32_16x16x32_f16(qf, bf, (f32x4){0.f,0.f,0.f,0.f}, 0, 0, 0);
    }

    float mx[4] = {-1e30f, -1e30f, -1e30f, -1e30f};
#pragma unroll
    for (int fk = 0; fk < 17; ++fk) {
        const int kk = fk * 16 + l15;
        const int k = lo + kk;
#pragma unroll
        for (int r = 0; r < 4; ++r) {
            const int q = q0 + qloc + l4 * 4 + r;
            const int d = k - q + 99;
            float v = -1e30f;
            if (kk < nk && d >= 0 && d < 199)
                v = sacc[fk][r] + (float)Scr[(qloc + l4 * 4 + r) * 296 + d];
            sacc[fk][r] = v;
            mx[r] = fmaxf(mx[r], v);
        }
    }
#pragma unroll
    for (int r = 0; r < 4; ++r) {
        mx[r] = fmaxf(mx[r], __shfl_xor(mx[r], 1));
        mx[r] = fmaxf(mx[r], __shfl_xor(mx[r], 2));
        mx[r] = fmaxf(mx[r], __shfl_xor(mx[r], 4));
        mx[r] = fmaxf(mx[r], __shfl_xor(mx[r], 8));
    }
    float sum[4] = {0.f, 0.f, 0.f, 0.f};
#pragma unroll
    for (int fk = 0; fk < 17; ++fk) {
        const int kk = fk * 16 + l15;
#pragma unroll
        for (int r = 0; r < 4; ++r) {
            const float p = __expf(sacc[fk][r] - mx[r]);
            sum[r] += p;
            Scr[(qloc + l4 * 4 + r) * 296 + kk] = (f16)p;
        }
    }
#pragma unroll
    for (int r = 0; r < 4; ++r)
        Scr[(qloc + l4 * 4 + r) * 296 + 272 + l15] = (f16)0;
#pragma unroll
    for (int r = 0; r < 4; ++r) {
        sum[r] += __shfl_xor(sum[r], 1);
        sum[r] += __shfl_xor(sum[r], 2);
        sum[r] += __shfl_xor(sum[r], 4);
        sum[r] += __shfl_xor(sum[r], 8);
    }

    f32x4 oacc[2] = {{0.f,0.f,0.f,0.f}, {0.f,0.f,0.f,0.f}};
#pragma unroll
    for (int ks = 0; ks < 9; ++ks) {
        const f16x8 pa = *(const f16x8*)&Scr[(qloc + l15) * 296 + ks * 32 + l4 * 8];
#pragma unroll
        for (int j = 0; j < 2; ++j) {
            const f16x8 vb = *(const f16x8*)&Vt[(j * 16 + l15) * 296 + ks * 32 + l4 * 8];
            oacc[j] = __builtin_amdgcn_mfma_f32_16x16x32_f16(pa, vb, oacc[j], 0, 0, 0);
        }
    }

    f16* ob = o + ((long)(b * 512 + q0 + qloc + l4 * 4)) * 256 + h * 32;
#pragma unroll
    for (int r = 0; r < 4; ++r) {
        const float inv = 1.f / sum[r];
#pragma unroll
        for (int j = 0; j < 2; ++j)
            ob[(long)r * 256 + j * 16 + l15] = (f16)(oacc[j][r] * inv);
    }
}

// ---------------- LayerNorm over 768, writes fp32 (residual) + f16 (next GEMM A) ----------------

__global__ __launch_bounds__(256) void ln_kernel(
    const float* __restrict__ src, const float* __restrict__ w, const float* __restrict__ bb,
    float* __restrict__ outF, f16* __restrict__ outH)
{
    __shared__ float red1[4], red2[4];
    const int row = blockIdx.x, tid = threadIdx.x;
    const float* x = src + (long)row * 768;
    float v0 = x[tid], v1 = x[tid + 256], v2 = x[tid + 512];
    float s = v0 + v1 + v2;
#pragma unroll
    for (int off = 32; off > 0; off >>= 1) s += __shfl_xor(s, off);
    if ((tid & 63) == 0) red1[tid >> 6] = s;
    __syncthreads();
    const float mu = (red1[0] + red1[1] + red1[2] + red1[3]) * (1.f / 768.f);
    const float d0 = v0 - mu, d1 = v1 - mu, d2 = v2 - mu;
    float ss = d0 * d0 + d1 * d1 + d2 * d2;
#pragma unroll
    for (int off = 32; off > 0; off >>= 1) ss += __shfl_xor(ss, off);
    if ((tid & 63) == 0) red2[tid >> 6] = ss;
    __syncthreads();
    const float var = (red2[0] + red2[1] + red2[2] + red2[3]) * (1.f / 768.f);
    const float inv = rsqrtf(var + 1e-5f);
    float y0 = d0 * inv * w[tid]       + bb[tid];
    float y1 = d1 * inv * w[tid + 256] + bb[tid + 256];
    float y2 = d2 * inv * w[tid + 512] + bb[tid + 512];
    long base = (long)row * 768;
    outF[base + tid] = y0; outF[base + tid + 256] = y1; outF[base + tid + 512] = y2;
    outH[base + tid] = (f16)y0; outH[base + tid + 256] = (f16)y1; outH[base + tid + 512] = (f16)y2;
}

// ---------------- split-K combine (sum 4 f16 partials + bias + residual) fused with LayerNorm ----------------

__global__ __launch_bounds__(256) void ln_sum4_kernel(
    const f16* __restrict__ p,        // [4][M_][768] f16 partials
    const float* __restrict__ bias, const float* __restrict__ res,
    const float* __restrict__ w, const float* __restrict__ bb,
    float* __restrict__ outF, f16* __restrict__ outH)
{
    __shared__ float red1[4], red2[4];
    const int row = blockIdx.x, tid = threadIdx.x;
    const long rb = (long)row * 768;
    float v[3];
#pragma unroll
    for (int i = 0; i < 3; ++i) {
        const int c = tid + i * 256;
        float s = bias[c] + res[rb + c];
#pragma unroll
        for (int zz = 0; zz < 4; ++zz) s += (float)p[((long)zz * M_ + row) * 768 + c];
        v[i] = s;
    }
    float s = v[0] + v[1] + v[2];
#pragma unroll
    for (int off = 32; off > 0; off >>= 1) s += __shfl_xor(s, off);
    if ((tid & 63) == 0) red1[tid >> 6] = s;
    __syncthreads();
    const float mu = (red1[0] + red1[1] + red1[2] + red1[3]) * (1.f / 768.f);
    const float d0 = v[0] - mu, d1 = v[1] - mu, d2 = v[2] - mu;
    float ss = d0 * d0 + d1 * d1 + d2 * d2;
#pragma unroll
    for (int off = 32; off > 0; off >>= 1) ss += __shfl_xor(ss, off);
    if ((tid & 63) == 0) red2[tid >> 6] = ss;
    __syncthreads();
    const float var = (red2[0] + red2[1] + red2[2] + red2[3]) * (1.f / 768.f);
    const float inv = rsqrtf(var + 1e-5f);
    float y0 = d0 * inv * w[tid]       + bb[tid];
    float y1 = d1 * inv * w[tid + 256] + bb[tid + 256];
    float y2 = d2 * inv * w[tid + 512] + bb[tid + 512];
    outF[rb + tid] = y0; outF[rb + tid + 256] = y1; outF[rb + tid + 512] = y2;
    outH[rb + tid] = (f16)y0; outH[rb + tid + 256] = (f16)y1; outH[rb + tid + 512] = (f16)y2;
}

// ---------------- host ----------------

extern "C" void kernel_launch(void* const* d_in, const int* in_sizes, int n_in,
                              void* d_out, int out_size, void* d_ws, size_t ws_size,
                              hipStream_t stream) {
    const float* x     = (const float*)d_in[0];
    const float* wq    = (const float*)d_in[1];
    const float* wk    = (const float*)d_in[2];
    const float* wv    = (const float*)d_in[3];
    const float* wo    = (const float*)d_in[4];
    const float* rel   = (const float*)d_in[5];
    const float* lin1w = (const float*)d_in[6];
    const float* lin1b = (const float*)d_in[7];
    const float* lin2w = (const float*)d_in[8];
    const float* lin2b = (const float*)d_in[9];
    const float* ln1w  = (const float*)d_in[10];
    const float* ln1b  = (const float*)d_in[11];
    const float* ln2w  = (const float*)d_in[12];
    const float* ln2b  = (const float*)d_in[13];
    const float* wout  = (const float*)d_in[14];
    const float* bout  = (const float*)d_in[15];

    char* base = (char*)d_ws;
    size_t off = 0;
    auto alloc = [&](size_t bytes) {
        void* p = base + off;
        off = (off + bytes + 255) & ~(size_t)255;
        return p;
    };
    f16*   xH    = (f16*)  alloc((size_t)M_ * 768 * 2);
    f16*   BTqkv = (f16*)  alloc((size_t)L_ * 768 * 768 * 2);
    f16*   BTwo  = (f16*)  alloc((size_t)L_ * 768 * 256 * 2);
    f16*   lin1H = (f16*)  alloc((size_t)L_ * 3072 * 768 * 2);
    f16*   lin2H = (f16*)  alloc((size_t)L_ * 768 * 3072 * 2);
    f16*   woutH = (f16*)  alloc((size_t)128 * 768 * 2);
    f16*   relH  = (f16*)  alloc((size_t)L_ * 8 * 208 * 32 * 2);
    f16*   qkvH  = (f16*)  alloc((size_t)M_ * 512 * 2);   // q|k
    f16*   vTbuf = (f16*)  alloc((size_t)B_ * 256 * 512 * 2);
    float* scrF  = (float*)alloc((size_t)M_ * 768 * 4);   // h1pre
    f16*   partH = (f16*)  alloc((size_t)4 * M_ * 768 * 2);  // FFN2 split-K f16 partials
    f16*   oH    = (f16*)  alloc((size_t)M_ * 256 * 2);
    float* ln1F  = (float*)alloc((size_t)M_ * 768 * 4);
    f16*   ln1H  = (f16*)  alloc((size_t)M_ * 768 * 2);
    f16*   ffH   = (f16*)  alloc((size_t)M_ * 3072 * 2);
    float* hF    = (float*)alloc((size_t)M_ * 768 * 4);
    f16*   hH    = (f16*)  alloc((size_t)M_ * 768 * 2);
    (void)ws_size; (void)in_sizes; (void)n_in; (void)out_size;

    pack_all_kernel<<<PKB_TOTAL, 256, 0, stream>>>(
        x, wq, wk, wv, wo, rel, lin1w, lin2w, wout,
        xH, BTqkv, BTwo, lin1H, lin2H, woutH, relH);

    for (int l = 0; l < L_; ++l) {
        const f16*   aIn   = (l == 0) ? xH : hH;
        const float* resIn = (l == 0) ? x  : hF;
        // QKV projection -> qkvH (q|k) + vTbuf; gemm8 wave-split-K, 768 blocks, nt=6
        gemm8_kernel<<<dim3(12, 64, 1), 256, 0, stream>>>(
            aIn, BTqkv + (size_t)l * 768 * 768, nullptr, nullptr, nullptr, qkvH, vTbuf,
            M_, 768, 768, 32, 512, 768);
        // banded MFMA attention -> oH (b,t,256) f16
        attn_kernel<<<dim3(8, 8, 4), 256, 0, stream>>>(qkvH, vTbuf, relH, l, oH);
        // attn output projection + residual -> scrF; gemm8, nt=2
        gemm8_kernel<<<dim3(12, 64, 1), 256, 0, stream>>>(
            oH, BTwo + (size_t)l * 768 * 256, nullptr, resIn, scrF, nullptr, nullptr,
            M_, 768, 256, 2 | 8, 768, 768);
        ln_kernel<<<M_, 256, 0, stream>>>(scrF, ln1w + l * 768, ln1b + l * 768, ln1F, ln1H);
        // FFN1: ReLU(ln1 @ lin1^T + b1) -> ffH; 128x64 tile, 768 blocks (3/CU)
        gemm7_kernel<128, 64><<<dim3(48, 16, 1), 256, 0, stream>>>(
            ln1H, lin1H + (size_t)l * 3072 * 768, lin1b + l * 3072, nullptr, nullptr, ffH, nullptr,
            M_, 3072, 768, 1 | 4 | 16, 3072, 3072);
        // FFN2 split-K x4 -> partH (f16 partials); 128x64 tile, 768 blocks, Kl=768 (nt=12)
        gemm7_kernel<128, 64><<<dim3(12, 16, 4), 256, 0, stream>>>(
            ffH, lin2H + (size_t)l * 768 * 3072, nullptr, nullptr, nullptr, partH, nullptr,
            M_, 768, 3072, 64, 768, 768);
        // combine + bias + ln1F residual + LayerNorm -> hF/hH
        ln_sum4_kernel<<<M_, 256, 0, stream>>>(partH, lin2b + l * 768, ln1F,
                                               ln2w + l * 768, ln2b + l * 768, hF, hH);
    }
    // final projection; gemm8, nt=6, grid (2,64)=128 blocks
    gemm8_kernel<<<dim3(2, 64, 1), 256, 0, stream>>>(
        hH, woutH, bout, nullptr, (float*)d_out, nullptr, nullptr,
        M_, 80, 768, 1 | 8, 80, 80);
}

// Round 15
// 501.611 us; speedup vs baseline: 1.0988x; 1.0988x over previous
//
#include <hip/hip_runtime.h>

typedef _Float16 f16;
typedef f16 f16x8 __attribute__((ext_vector_type(8)));
typedef f16 f16x4 __attribute__((ext_vector_type(4)));
typedef float f32x4 __attribute__((ext_vector_type(4)));

#define B_ 4
#define T_ 512
#define DM_ 768
#define H_ 8
#define DQ_ 32
#define FF_ 3072
#define L_ 6
#define OUT_ 80
#define M_ (B_*T_)   // 2048 tokens

// async global->LDS, 16B per lane; LDS dest is wave-uniform base + lane*16 (linear)
__device__ __forceinline__ void gload16(const f16* g, f16* l) {
    __builtin_amdgcn_global_load_lds(
        (const __attribute__((address_space(1))) unsigned int*)g,
        (__attribute__((address_space(3))) unsigned int*)l, 16, 0, 0);
}

template<int N> __device__ __forceinline__ void wait_vm() {
    if constexpr (N == 0)      asm volatile("s_waitcnt vmcnt(0)" ::: "memory");
    else if constexpr (N == 3) asm volatile("s_waitcnt vmcnt(3)" ::: "memory");
    else if constexpr (N == 4) asm volatile("s_waitcnt vmcnt(4)" ::: "memory");
    else if constexpr (N == 6) asm volatile("s_waitcnt vmcnt(6)" ::: "memory");
    else                       asm volatile("s_waitcnt vmcnt(0)" ::: "memory");
}

// ---------------- single fused pack kernel (R13 exact) ----------------

#define PKU_X  98304L                      // x: units of 16 floats
#define PKU_L1 (PKU_X + 884736L)           // + lin1w
#define PKU_L2 (PKU_L1 + 884736L)          // + lin2w = 1867776
#define PKB_VEC 7296                       // PKU_L2 / 256
#define PKB_LIN 1632                       // (98304 woutH + 319488 relH) / 256
#define PKB_QKV 864                        // 72 (l,sec,hpair) groups * 12 k-tiles of 64
#define PKB_WO  1152                       // 6l * 8 k'-tiles * 24 n-tiles (32x32)
#define PKB_TOTAL (PKB_VEC + PKB_LIN + PKB_QKV + PKB_WO)

__global__ void pack_all_kernel(
    const float* __restrict__ x, const float* __restrict__ wq, const float* __restrict__ wk,
    const float* __restrict__ wv, const float* __restrict__ wo, const float* __restrict__ rel,
    const float* __restrict__ lin1w, const float* __restrict__ lin2w, const float* __restrict__ wout,
    f16* __restrict__ xH, f16* __restrict__ BTqkv, f16* __restrict__ BTwo,
    f16* __restrict__ lin1H, f16* __restrict__ lin2H, f16* __restrict__ woutH, f16* __restrict__ relH)
{
    __shared__ float tile[64 * 65];
    const int bid = blockIdx.x, tid = threadIdx.x;
    if (bid < PKB_VEC) {
        const long u = (long)bid * 256 + tid;   // unit of 16 floats
        const float* src; f16* dst; long off;
        if (u < PKU_X)       { src = x;     dst = xH;    off = u; }
        else if (u < PKU_L1) { src = lin1w; dst = lin1H; off = u - PKU_X; }
        else                 { src = lin2w; dst = lin2H; off = u - PKU_L1; }
        const float4 v0 = ((const float4*)src)[off * 4];
        const float4 v1 = ((const float4*)src)[off * 4 + 1];
        const float4 v2 = ((const float4*)src)[off * 4 + 2];
        const float4 v3 = ((const float4*)src)[off * 4 + 3];
        f16x8 o0, o1;
        o0[0] = (f16)v0.x; o0[1] = (f16)v0.y; o0[2] = (f16)v0.z; o0[3] = (f16)v0.w;
        o0[4] = (f16)v1.x; o0[5] = (f16)v1.y; o0[6] = (f16)v1.z; o0[7] = (f16)v1.w;
        o1[0] = (f16)v2.x; o1[1] = (f16)v2.y; o1[2] = (f16)v2.z; o1[3] = (f16)v2.w;
        o1[4] = (f16)v3.x; o1[5] = (f16)v3.y; o1[6] = (f16)v3.z; o1[7] = (f16)v3.w;
        ((f16x8*)dst)[off * 2]     = o0;
        ((f16x8*)dst)[off * 2 + 1] = o1;
    } else if (bid < PKB_VEC + PKB_LIN) {
        const long u = (long)(bid - PKB_VEC) * 256 + tid;
        if (u < 98304) {            // woutH zero-padded (128,768)
            const int k = (int)(u % 768), n = (int)(u / 768);
            woutH[u] = (n < OUT_) ? (f16)wout[n * 768 + k] : (f16)0;
        } else {                    // relH[l][h][208][32], rows d>=199 zero
            const long v2 = u - 98304;
            const int a = (int)(v2 & 31);
            const long t = v2 >> 5;
            const int d = (int)(t % 208);
            const int lh = (int)(t / 208);
            relH[v2] = (d < 199) ? (f16)rel[((long)lh * 199 + d) * 32 + a] : (f16)0;
        }
    } else if (bid < PKB_VEC + PKB_LIN + PKB_QKV) {
        // BTqkv: per (l,sec,h-pair), transpose a 64k x 64n fp32 region (two 64x32 head panels)
        const int g = bid - (PKB_VEC + PKB_LIN);
        const int kb = g % 12;
        const int grp = g / 12;
        const int hp = grp & 3, sec = (grp >> 2) % 3, l = grp / 12;
        const float* w = (sec == 0) ? wq : (sec == 1 ? wk : wv);
        const float scale = (sec == 0) ? 0.17677669529663687f : 1.f;
#pragma unroll
        for (int hh = 0; hh < 2; ++hh) {
            const float* src = w + (((long)l * 8 + hp * 2 + hh) * 768 + kb * 64) * 32;
#pragma unroll
            for (int p = 0; p < 2; ++p) {
                const int kk = p * 32 + (tid >> 3), a = (tid & 7) * 4;
                const float4 v = *(const float4*)(src + (long)kk * 32 + a);
                float* t = &tile[kk * 65 + hh * 32 + a];
                t[0] = v.x * scale; t[1] = v.y * scale; t[2] = v.z * scale; t[3] = v.w * scale;
            }
        }
        __syncthreads();
        f16* dst = BTqkv + ((long)l * 768 + sec * 256 + hp * 64) * 768 + kb * 64;
#pragma unroll
        for (int p = 0; p < 2; ++p) {
            const int nn = p * 32 + (tid >> 3), k8 = (tid & 7) * 8;
            f16x8 o;
#pragma unroll
            for (int e = 0; e < 8; ++e) o[e] = (f16)tile[(k8 + e) * 65 + nn];
            *(f16x8*)(dst + (long)nn * 768 + k8) = o;
        }
    } else {
        // BTwo: transpose wo[l][k'][n] 32x32 fp32 tiles -> BTwo[l][n][k']
        const int g = bid - (PKB_VEC + PKB_LIN + PKB_QKV);
        const int nb = g % 24;
        const int tmp = g / 24;
        const int kb2 = tmp % 8, l = tmp / 8;
        const float* src = wo + ((long)l * 256 + kb2 * 32) * 768 + nb * 32;
        {
            const int r = tid >> 3, c = (tid & 7) * 4;
            const float4 v = *(const float4*)(src + (long)r * 768 + c);
            float* t = &tile[r * 65 + c];
            t[0] = v.x; t[1] = v.y; t[2] = v.z; t[3] = v.w;
        }
        __syncthreads();
        if (tid < 128) {
            const int n = tid >> 2, k8 = (tid & 3) * 8;
            f16x8 o;
#pragma unroll
            for (int e = 0; e < 8; ++e) o[e] = (f16)tile[(k8 + e) * 65 + n];
            f16* dst = BTwo + ((long)l * 768 + nb * 32 + n) * 256 + kb2 * 32 + k8;
            *(f16x8*)dst = o;
        }
    }
}

// ---------------- bijective XCD chunk swizzle (per z-slice nwg %8==0 for all our grids) ----------------
__device__ __forceinline__ void xcd_tile(int BM, int BN, int& m0, int& n0) {
    const int gx = gridDim.x;
    const int id = blockIdx.y * gx + blockIdx.x;
    const int cpx = (gx * gridDim.y) >> 3;
    const int t = (id & 7) * cpx + (id >> 3);
    m0 = (t / gx) * BM;
    n0 = (t % gx) * BN;
}

// ---------------- gemm7: 2-buffer, 2-barrier, counted vmcnt, XOR-swizzled LDS ----------------
// mode: 1=+bias, 2=+res, 4=ReLU, 8=outF, 16=outH, 32=qkv epilogue, 64=split-K f16 partial (outH)

template<int BM, int BN>
__global__ __launch_bounds__(256) void gemm7_kernel(
    const f16* __restrict__ A, const f16* __restrict__ Bt,
    const float* __restrict__ bias, const float* __restrict__ res,
    float* __restrict__ outF, f16* __restrict__ outH, f16* __restrict__ vTout,
    int M, int N, int K, int mode, int ldOut, int nMax)
{
    constexpr int IA = BM / 32;
    constexpr int JF = BN / 32;
    constexpr int LA = BM / 32;
    constexpr int LB = BN / 32;
    constexpr int L  = LA + LB;
    __shared__ __align__(16) f16 As[2][BM * 64];
    __shared__ __align__(16) f16 Bs[2][BN * 64];
    const int tid = threadIdx.x;
    const int wave = tid >> 6, lane = tid & 63;
    int m0, n0; xcd_tile(BM, BN, m0, n0);
    const int z = blockIdx.z;
    const int Kl = K / (int)gridDim.z;
    const int kb = z * Kl;
    const int nt = Kl / 64;
    const int wr = wave >> 1, wc = wave & 1;
    const int l15 = lane & 15, l4 = lane >> 4;
    const int lrow = lane >> 3;
    const int lcol = ((lane & 7) ^ (lane >> 3)) * 8;   // pre-swizzled source granule

    const f16* Abase = A  + (long)(m0 + lrow) * K + kb + lcol;
    const f16* Bbase = Bt + (long)(n0 + lrow) * K + kb + lcol;

    f32x4 acc[IA][JF];
#pragma unroll
    for (int i = 0; i < IA; ++i)
#pragma unroll
        for (int j = 0; j < JF; ++j) acc[i][j] = (f32x4){0.f, 0.f, 0.f, 0.f};

    auto stage = [&](int buf, int k0) {
#pragma unroll
        for (int i = 0; i < LA; ++i) {
            const int c = wave + 4 * i;
            gload16(Abase + (long)c * 8 * K + k0, &As[buf][c * 512]);
        }
#pragma unroll
        for (int i = 0; i < LB; ++i) {
            const int c = wave + 4 * i;
            gload16(Bbase + (long)c * 8 * K + k0, &Bs[buf][c * 512]);
        }
    };

    stage(0, 0);
    int cur = 0;
    for (int t = 0; t < nt; ++t) {
        if (t + 1 < nt) { stage(cur ^ 1, (t + 1) * 64); wait_vm<L>(); }
        else            { wait_vm<0>(); }
        __builtin_amdgcn_s_barrier();
#pragma unroll
        for (int s = 0; s < 2; ++s) {
            f16x8 af[IA], bf[JF];
#pragma unroll
            for (int i = 0; i < IA; ++i) {
                const int row = wr * (BM / 2) + i * 16 + l15;
                af[i] = *(const f16x8*)&As[cur][row * 64 + (((s * 4 + l4) ^ (l15 & 7)) * 8)];
            }
#pragma unroll
            for (int j = 0; j < JF; ++j) {
                const int row = wc * (BN / 2) + j * 16 + l15;
                bf[j] = *(const f16x8*)&Bs[cur][row * 64 + (((s * 4 + l4) ^ (l15 & 7)) * 8)];
            }
#pragma unroll
            for (int i = 0; i < IA; ++i)
#pragma unroll
                for (int j = 0; j < JF; ++j)
                    acc[i][j] = __builtin_amdgcn_mfma_f32_16x16x32_f16(af[i], bf[j], acc[i][j], 0, 0, 0);
        }
        __builtin_amdgcn_s_barrier();
        cur ^= 1;
    }

#pragma unroll
    for (int i = 0; i < IA; ++i) {
#pragma unroll
        for (int j = 0; j < JF; ++j) {
            const int col = n0 + wc * (BN / 2) + j * 16 + l15;
            if (mode & 32) {
#pragma unroll
                for (int r = 0; r < 4; ++r) {
                    const int row = m0 + wr * (BM / 2) + i * 16 + l4 * 4 + r;
                    float v = acc[i][j][r];
                    if (col < 512) {
                        outH[(long)row * 512 + col] = (f16)v;
                    } else {
                        const int bb = row >> 9, t = row & 511;
                        vTout[((long)(bb * 256 + (col - 512))) * 512 + t] = (f16)v;
                    }
                }
            } else if (mode & 64) {
                f16* po = outH + (long)z * M * ldOut;   // f16 split-K partial
#pragma unroll
                for (int r = 0; r < 4; ++r) {
                    const int row = m0 + wr * (BM / 2) + i * 16 + l4 * 4 + r;
                    po[(long)row * ldOut + col] = (f16)acc[i][j][r];
                }
            } else if (col < nMax) {
                const float bvv = (mode & 1) ? bias[col] : 0.f;
#pragma unroll
                for (int r = 0; r < 4; ++r) {
                    const int row = m0 + wr * (BM / 2) + i * 16 + l4 * 4 + r;
                    float v = acc[i][j][r] + bvv;
                    if (mode & 2) v += res[(long)row * N + col];
                    if (mode & 4) v = fmaxf(v, 0.f);
                    if (mode & 8)  outF[(long)row * ldOut + col] = v;
                    if (mode & 16) outH[(long)row * ldOut + col] = (f16)v;
                }
            }
        }
    }
}

// ---------------- banded attention via MFMA (R13 exact) ----------------

__global__ __launch_bounds__(256) void attn_kernel(
    const f16* __restrict__ qkvH, const f16* __restrict__ vT,
    const f16* __restrict__ relH, int l, f16* __restrict__ o)
{
    __shared__ __align__(16) f16 Ks[272 * 40];
    __shared__ __align__(16) f16 Vt[32 * 296];
    __shared__ __align__(16) f16 Scr[64 * 296];
    const int tid = threadIdx.x;
    const int qb = blockIdx.x, h = blockIdx.y, b = blockIdx.z;
    const int q0 = qb * 64;
    int lo = q0 - 99; lo = (lo > 0) ? (lo & ~7) : 0;
    const int hi = min(512, q0 + 163);
    const int nk = hi - lo;                             // <= 269

    for (int idx = tid; idx < 272 * 4; idx += 256) {
        const int r = idx >> 2, c = idx & 3;
        f16x8 v = {};
        if (r < nk)
            v = *(const f16x8*)(qkvH + ((long)(b * 512 + lo + r)) * 512 + 256 + h * 32 + c * 8);
        *(f16x8*)&Ks[r * 40 + c * 8] = v;
    }
    for (int idx = tid; idx < 32 * 36; idx += 256) {
        const int a = idx / 36, k8 = idx % 36;
        f16x8 v = {};
        const int kbase = k8 * 8;
        if (kbase < nk) {
            const f16* src = vT + ((long)(b * 256 + h * 32 + a)) * 512 + lo + kbase;
            if (kbase + 8 <= nk) {
                v = *(const f16x8*)src;
            } else {
#pragma unroll
                for (int e = 0; e < 8; ++e) if (kbase + e < nk) v[e] = src[e];
            }
        }
        *(f16x8*)&Vt[a * 296 + kbase] = v;
    }

    const int wave = tid >> 6, lane = tid & 63;
    const int l15 = lane & 15, l4 = lane >> 4;
    const int qloc = wave * 16;

    const f16x8 qf = *(const f16x8*)(qkvH + ((long)(b * 512 + q0 + qloc + l15)) * 512 + h * 32 + l4 * 8);

    const f16* relh = relH + ((long)(l * 8 + h)) * 208 * 32;
    {
        f32x4 racc[13];
#pragma unroll
        for (int fd = 0; fd < 13; ++fd) {
            const f16x8 bf = *(const f16x8*)(relh + (fd * 16 + l15) * 32 + l4 * 8);
            racc[fd] = __builtin_amdgcn_mfma_f32_16x16x32_f16(qf, bf, (f32x4){0.f,0.f,0.f,0.f}, 0, 0, 0);
        }
#pragma unroll
        for (int fd = 0; fd < 13; ++fd)
#pragma unroll
            for (int r = 0; r < 4; ++r)
                Scr[(qloc + l4 * 4 + r) * 296 + fd * 16 + l15] = (f16)racc[fd][r];
    }
    __syncthreads();

    f32x4 sacc[17];
#pragma unroll
    for (int fk = 0; fk < 17; ++fk) {
        const f16x8 bf = *(const f16x8*)&Ks[(fk * 16 + l15) * 40 + l4 * 8];
        sacc[fk] = __builtin_amdgcn_mfma_f32_16x16x32_f16(qf, bf, (f32x4){0.f,0.f,0.f,0.f}, 0, 0, 0);
    }

    float mx[4] = {-1e30f, -1e30f, -1e30f, -1e30f};
#pragma unroll
    for (int fk = 0; fk < 17; ++fk) {
        const int kk = fk * 16 + l15;
        const int k = lo + kk;
#pragma unroll
        for (int r = 0; r < 4; ++r) {
            const int q = q0 + qloc + l4 * 4 + r;
            const int d = k - q + 99;
            float v = -1e30f;
            if (kk < nk && d >= 0 && d < 199)
                v = sacc[fk][r] + (float)Scr[(qloc + l4 * 4 + r) * 296 + d];
            sacc[fk][r] = v;
            mx[r] = fmaxf(mx[r], v);
        }
    }
#pragma unroll
    for (int r = 0; r < 4; ++r) {
        mx[r] = fmaxf(mx[r], __shfl_xor(mx[r], 1));
        mx[r] = fmaxf(mx[r], __shfl_xor(mx[r], 2));
        mx[r] = fmaxf(mx[r], __shfl_xor(mx[r], 4));
        mx[r] = fmaxf(mx[r], __shfl_xor(mx[r], 8));
    }
    float sum[4] = {0.f, 0.f, 0.f, 0.f};
#pragma unroll
    for (int fk = 0; fk < 17; ++fk) {
        const int kk = fk * 16 + l15;
#pragma unroll
        for (int r = 0; r < 4; ++r) {
            const float p = __expf(sacc[fk][r] - mx[r]);
            sum[r] += p;
            Scr[(qloc + l4 * 4 + r) * 296 + kk] = (f16)p;
        }
    }
#pragma unroll
    for (int r = 0; r < 4; ++r)
        Scr[(qloc + l4 * 4 + r) * 296 + 272 + l15] = (f16)0;
#pragma unroll
    for (int r = 0; r < 4; ++r) {
        sum[r] += __shfl_xor(sum[r], 1);
        sum[r] += __shfl_xor(sum[r], 2);
        sum[r] += __shfl_xor(sum[r], 4);
        sum[r] += __shfl_xor(sum[r], 8);
    }

    f32x4 oacc[2] = {{0.f,0.f,0.f,0.f}, {0.f,0.f,0.f,0.f}};
#pragma unroll
    for (int ks = 0; ks < 9; ++ks) {
        const f16x8 pa = *(const f16x8*)&Scr[(qloc + l15) * 296 + ks * 32 + l4 * 8];
#pragma unroll
        for (int j = 0; j < 2; ++j) {
            const f16x8 vb = *(const f16x8*)&Vt[(j * 16 + l15) * 296 + ks * 32 + l4 * 8];
            oacc[j] = __builtin_amdgcn_mfma_f32_16x16x32_f16(pa, vb, oacc[j], 0, 0, 0);
        }
    }

    f16* ob = o + ((long)(b * 512 + q0 + qloc + l4 * 4)) * 256 + h * 32;
#pragma unroll
    for (int r = 0; r < 4; ++r) {
        const float inv = 1.f / sum[r];
#pragma unroll
        for (int j = 0; j < 2; ++j)
            ob[(long)r * 256 + j * 16 + l15] = (f16)(oacc[j][r] * inv);
    }
}

// ---------------- LayerNorm over 768, writes fp32 (residual) + f16 (next GEMM A) ----------------

__global__ __launch_bounds__(256) void ln_kernel(
    const float* __restrict__ src, const float* __restrict__ w, const float* __restrict__ bb,
    float* __restrict__ outF, f16* __restrict__ outH)
{
    __shared__ float red1[4], red2[4];
    const int row = blockIdx.x, tid = threadIdx.x;
    const float* x = src + (long)row * 768;
    float v0 = x[tid], v1 = x[tid + 256], v2 = x[tid + 512];
    float s = v0 + v1 + v2;
#pragma unroll
    for (int off = 32; off > 0; off >>= 1) s += __shfl_xor(s, off);
    if ((tid & 63) == 0) red1[tid >> 6] = s;
    __syncthreads();
    const float mu = (red1[0] + red1[1] + red1[2] + red1[3]) * (1.f / 768.f);
    const float d0 = v0 - mu, d1 = v1 - mu, d2 = v2 - mu;
    float ss = d0 * d0 + d1 * d1 + d2 * d2;
#pragma unroll
    for (int off = 32; off > 0; off >>= 1) ss += __shfl_xor(ss, off);
    if ((tid & 63) == 0) red2[tid >> 6] = ss;
    __syncthreads();
    const float var = (red2[0] + red2[1] + red2[2] + red2[3]) * (1.f / 768.f);
    const float inv = rsqrtf(var + 1e-5f);
    float y0 = d0 * inv * w[tid]       + bb[tid];
    float y1 = d1 * inv * w[tid + 256] + bb[tid + 256];
    float y2 = d2 * inv * w[tid + 512] + bb[tid + 512];
    long base = (long)row * 768;
    outF[base + tid] = y0; outF[base + tid + 256] = y1; outF[base + tid + 512] = y2;
    outH[base + tid] = (f16)y0; outH[base + tid + 256] = (f16)y1; outH[base + tid + 512] = (f16)y2;
}

// ---------------- split-K combine (sum 4 f16 partials + bias + residual) fused with LayerNorm ----------------

__global__ __launch_bounds__(256) void ln_sum4_kernel(
    const f16* __restrict__ p,        // [4][M_][768] f16 partials
    const float* __restrict__ bias, const float* __restrict__ res,
    const float* __restrict__ w, const float* __restrict__ bb,
    float* __restrict__ outF, f16* __restrict__ outH)
{
    __shared__ float red1[4], red2[4];
    const int row = blockIdx.x, tid = threadIdx.x;
    const long rb = (long)row * 768;
    float v[3];
#pragma unroll
    for (int i = 0; i < 3; ++i) {
        const int c = tid + i * 256;
        float s = bias[c] + res[rb + c];
#pragma unroll
        for (int zz = 0; zz < 4; ++zz) s += (float)p[((long)zz * M_ + row) * 768 + c];
        v[i] = s;
    }
    float s = v[0] + v[1] + v[2];
#pragma unroll
    for (int off = 32; off > 0; off >>= 1) s += __shfl_xor(s, off);
    if ((tid & 63) == 0) red1[tid >> 6] = s;
    __syncthreads();
    const float mu = (red1[0] + red1[1] + red1[2] + red1[3]) * (1.f / 768.f);
    const float d0 = v[0] - mu, d1 = v[1] - mu, d2 = v[2] - mu;
    float ss = d0 * d0 + d1 * d1 + d2 * d2;
#pragma unroll
    for (int off = 32; off > 0; off >>= 1) ss += __shfl_xor(ss, off);
    if ((tid & 63) == 0) red2[tid >> 6] = ss;
    __syncthreads();
    const float var = (red2[0] + red2[1] + red2[2] + red2[3]) * (1.f / 768.f);
    const float inv = rsqrtf(var + 1e-5f);
    float y0 = d0 * inv * w[tid]       + bb[tid];
    float y1 = d1 * inv * w[tid + 256] + bb[tid + 256];
    float y2 = d2 * inv * w[tid + 512] + bb[tid + 512];
    outF[rb + tid] = y0; outF[rb + tid + 256] = y1; outF[rb + tid + 512] = y2;
    outH[rb + tid] = (f16)y0; outH[rb + tid + 256] = (f16)y1; outH[rb + tid + 512] = (f16)y2;
}

// ---------------- host ----------------

extern "C" void kernel_launch(void* const* d_in, const int* in_sizes, int n_in,
                              void* d_out, int out_size, void* d_ws, size_t ws_size,
                              hipStream_t stream) {
    const float* x     = (const float*)d_in[0];
    const float* wq    = (const float*)d_in[1];
    const float* wk    = (const float*)d_in[2];
    const float* wv    = (const float*)d_in[3];
    const float* wo    = (const float*)d_in[4];
    const float* rel   = (const float*)d_in[5];
    const float* lin1w = (const float*)d_in[6];
    const float* lin1b = (const float*)d_in[7];
    const float* lin2w = (const float*)d_in[8];
    const float* lin2b = (const float*)d_in[9];
    const float* ln1w  = (const float*)d_in[10];
    const float* ln1b  = (const float*)d_in[11];
    const float* ln2w  = (const float*)d_in[12];
    const float* ln2b  = (const float*)d_in[13];
    const float* wout  = (const float*)d_in[14];
    const float* bout  = (const float*)d_in[15];

    char* base = (char*)d_ws;
    size_t off = 0;
    auto alloc = [&](size_t bytes) {
        void* p = base + off;
        off = (off + bytes + 255) & ~(size_t)255;
        return p;
    };
    f16*   xH    = (f16*)  alloc((size_t)M_ * 768 * 2);
    f16*   BTqkv = (f16*)  alloc((size_t)L_ * 768 * 768 * 2);
    f16*   BTwo  = (f16*)  alloc((size_t)L_ * 768 * 256 * 2);
    f16*   lin1H = (f16*)  alloc((size_t)L_ * 3072 * 768 * 2);
    f16*   lin2H = (f16*)  alloc((size_t)L_ * 768 * 3072 * 2);
    f16*   woutH = (f16*)  alloc((size_t)128 * 768 * 2);
    f16*   relH  = (f16*)  alloc((size_t)L_ * 8 * 208 * 32 * 2);
    f16*   qkvH  = (f16*)  alloc((size_t)M_ * 512 * 2);   // q|k
    f16*   vTbuf = (f16*)  alloc((size_t)B_ * 256 * 512 * 2);
    float* scrF  = (float*)alloc((size_t)M_ * 768 * 4);   // h1pre
    f16*   partH = (f16*)  alloc((size_t)4 * M_ * 768 * 2);  // FFN2 split-K f16 partials
    f16*   oH    = (f16*)  alloc((size_t)M_ * 256 * 2);
    float* ln1F  = (float*)alloc((size_t)M_ * 768 * 4);
    f16*   ln1H  = (f16*)  alloc((size_t)M_ * 768 * 2);
    f16*   ffH   = (f16*)  alloc((size_t)M_ * 3072 * 2);
    float* hF    = (float*)alloc((size_t)M_ * 768 * 4);
    f16*   hH    = (f16*)  alloc((size_t)M_ * 768 * 2);
    (void)ws_size; (void)in_sizes; (void)n_in; (void)out_size;

    pack_all_kernel<<<PKB_TOTAL, 256, 0, stream>>>(
        x, wq, wk, wv, wo, rel, lin1w, lin2w, wout,
        xH, BTqkv, BTwo, lin1H, lin2H, woutH, relH);

    for (int l = 0; l < L_; ++l) {
        const f16*   aIn   = (l == 0) ? xH : hH;
        const float* resIn = (l == 0) ? x  : hF;
        // QKV projection -> qkvH (q|k) + vTbuf (V transposed); 32x64, 768 blocks
        gemm7_kernel<32, 64><<<dim3(12, 64, 1), 256, 0, stream>>>(
            aIn, BTqkv + (size_t)l * 768 * 768, nullptr, nullptr, nullptr, qkvH, vTbuf,
            M_, 768, 768, 32, 512, 768);
        // banded MFMA attention -> oH (b,t,256) f16
        attn_kernel<<<dim3(8, 8, 4), 256, 0, stream>>>(qkvH, vTbuf, relH, l, oH);
        // attn output projection + residual -> scrF (h1pre); 32x64, 768 blocks
        gemm7_kernel<32, 64><<<dim3(12, 64, 1), 256, 0, stream>>>(
            oH, BTwo + (size_t)l * 768 * 256, nullptr, resIn, scrF, nullptr, nullptr,
            M_, 768, 256, 2 | 8, 768, 768);
        ln_kernel<<<M_, 256, 0, stream>>>(scrF, ln1w + l * 768, ln1b + l * 768, ln1F, ln1H);
        // FFN1: ReLU(ln1 @ lin1^T + b1) -> ffH; 128x64 tile, 768 blocks (3/CU)
        gemm7_kernel<128, 64><<<dim3(48, 16, 1), 256, 0, stream>>>(
            ln1H, lin1H + (size_t)l * 3072 * 768, lin1b + l * 3072, nullptr, nullptr, ffH, nullptr,
            M_, 3072, 768, 1 | 4 | 16, 3072, 3072);
        // FFN2 split-K x4 -> partH (f16 partials); 128x64 tile, 768 blocks, Kl=768 (nt=12)
        gemm7_kernel<128, 64><<<dim3(12, 16, 4), 256, 0, stream>>>(
            ffH, lin2H + (size_t)l * 768 * 3072, nullptr, nullptr, nullptr, partH, nullptr,
            M_, 768, 3072, 64, 768, 768);
        // combine + bias + ln1F residual + LayerNorm -> hF/hH
        ln_sum4_kernel<<<M_, 256, 0, stream>>>(partH, lin2b + l * 768, ln1F,
                                               ln2w + l * 768, ln2b + l * 768, hF, hH);
    }
    // final projection via MFMA GEMM (w_out zero-padded to 128 rows)
    gemm7_kernel<32, 64><<<dim3(2, 64, 1), 256, 0, stream>>>(
        hH, woutH, bout, nullptr, (float*)d_out, nullptr, nullptr,
        M_, 80, 768, 1 | 8, 80, 80);
}